// Round 1
// baseline (812.174 us; speedup 1.0000x reference)
//
#include <hip/hip_runtime.h>
#include <stdint.h>

#define NR 65536
#define DD 256
#define KC 1024
#define KD (KC * DD)

typedef __attribute__((ext_vector_type(8))) short bf16x8;
typedef __attribute__((ext_vector_type(4))) float f32x4;

__device__ inline unsigned short f2bf(float f) {
  union { float f; uint32_t u; } v; v.f = f;
  uint32_t u = v.u;
  u += 0x7FFFu + ((u >> 16) & 1u);
  return (unsigned short)(u >> 16);
}
__device__ inline float bf2f(unsigned short h) {
  union { uint32_t u; float f; } v; v.u = ((uint32_t)h) << 16;
  return v.f;
}

// ---------------- codebook prep: bf16 split + c2 (double -> f32) ----------------
__global__ __launch_bounds__(256) void k_prep(const float* __restrict__ cbs,
                                              unsigned short* __restrict__ ch,
                                              unsigned short* __restrict__ cl,
                                              float* __restrict__ c2) {
  int code = blockIdx.x * 4 + (threadIdx.x >> 6);  // 0..3071 over [3][1024]
  int lane = threadIdx.x & 63;
  float4 v = ((const float4*)(cbs + (size_t)code * DD))[lane];
  ushort4 h, l;
  h.x = f2bf(v.x); l.x = f2bf(v.x - bf2f(h.x));
  h.y = f2bf(v.y); l.y = f2bf(v.y - bf2f(h.y));
  h.z = f2bf(v.z); l.z = f2bf(v.z - bf2f(h.z));
  h.w = f2bf(v.w); l.w = f2bf(v.w - bf2f(h.w));
  ((ushort4*)(ch + (size_t)code * DD))[lane] = h;
  ((ushort4*)(cl + (size_t)code * DD))[lane] = l;
  double s = (double)v.x * v.x + (double)v.y * v.y + (double)v.z * v.z + (double)v.w * v.w;
  for (int off = 1; off < 64; off <<= 1) s += __shfl_xor(s, off);
  if (lane == 0) c2[code] = (float)s;
}

// ---------------- row norms ||z||^2 (double -> f32) ----------------
__global__ __launch_bounds__(256) void k_l2(const float* __restrict__ z,
                                            float* __restrict__ l2) {
  int row = blockIdx.x * 4 + (threadIdx.x >> 6);
  int lane = threadIdx.x & 63;
  float4 v = ((const float4*)(z + (size_t)row * DD))[lane];
  double s = (double)v.x * v.x + (double)v.y * v.y + (double)v.z * v.z + (double)v.w * v.w;
  for (int off = 1; off < 64; off <<= 1) s += __shfl_xor(s, off);
  if (lane == 0) l2[row] = (float)s;
}

// ---------------- distance GEMM (split-bf16 MFMA) + fused argmin ----------------
// grid: 4096 = 512 rowblocks x 8 codeblocks; block 256 (4 waves, 2x2 of 64x64)
__global__ __launch_bounds__(256) void k_gemm(const float* __restrict__ z,
                                              const unsigned short* __restrict__ chS,
                                              const unsigned short* __restrict__ clS,
                                              const float* __restrict__ c2S,
                                              const float* __restrict__ l2g,
                                              float* __restrict__ pval,
                                              int* __restrict__ pidx) {
  constexpr int LDT = 40;  // LDS row stride in elems (80 B) -> pad kills bank conflicts
  __shared__ unsigned short s_zh[128 * LDT];
  __shared__ unsigned short s_zl[128 * LDT];
  __shared__ unsigned short s_ch[128 * LDT];
  __shared__ unsigned short s_cl[128 * LDT];
  __shared__ float s_l2[128];
  __shared__ float s_c2[128];
  __shared__ float s_wv[256];
  __shared__ int s_wk[256];

  const int tid = threadIdx.x;
  const int rowblk = blockIdx.x >> 3;
  const int codeblk = blockIdx.x & 7;
  const int row0 = rowblk * 128;
  const int code0 = codeblk * 128;

  if (tid < 128) {
    s_l2[tid] = l2g[row0 + tid];
    s_c2[tid] = c2S[code0 + tid];
  }

  f32x4 acc[4][4];
#pragma unroll
  for (int i = 0; i < 4; i++)
#pragma unroll
    for (int j = 0; j < 4; j++) acc[i][j] = f32x4{0.f, 0.f, 0.f, 0.f};

  const int wv = tid >> 6;
  const int wr = wv >> 1, wc = wv & 1;
  const int lane = tid & 63;
  const int l15 = lane & 15;
  const int lk = (lane >> 4) * 8;  // k offset within 32

  for (int dc = 0; dc < 8; ++dc) {  // 8 chunks of 32 over D=256
    // --- stage A: z f32 -> zh/zl bf16 into LDS ---
#pragma unroll
    for (int p = 0; p < 4; ++p) {
      int arow = p * 32 + (tid >> 3);
      int aseg = tid & 7;
      float4 v = *((const float4*)(z + (size_t)(row0 + arow) * DD + dc * 32 + aseg * 4));
      ushort4 h, l;
      h.x = f2bf(v.x); l.x = f2bf(v.x - bf2f(h.x));
      h.y = f2bf(v.y); l.y = f2bf(v.y - bf2f(h.y));
      h.z = f2bf(v.z); l.z = f2bf(v.z - bf2f(h.z));
      h.w = f2bf(v.w); l.w = f2bf(v.w - bf2f(h.w));
      *((ushort4*)&s_zh[arow * LDT + aseg * 4]) = h;
      *((ushort4*)&s_zl[arow * LDT + aseg * 4]) = l;
    }
    // --- stage B: pre-split ch/cl bf16 into LDS ---
#pragma unroll
    for (int p = 0; p < 2; ++p) {
      int brow = p * 64 + (tid >> 2);
      int bseg = tid & 3;
      bf16x8 h = *((const bf16x8*)(chS + (size_t)(code0 + brow) * DD + dc * 32 + bseg * 8));
      bf16x8 l = *((const bf16x8*)(clS + (size_t)(code0 + brow) * DD + dc * 32 + bseg * 8));
      *((bf16x8*)&s_ch[brow * LDT + bseg * 8]) = h;
      *((bf16x8*)&s_cl[brow * LDT + bseg * 8]) = l;
    }
    __syncthreads();

    bf16x8 ah[4], al[4], bh[4], bl[4];
#pragma unroll
    for (int i = 0; i < 4; i++) {
      int r = wr * 64 + i * 16 + l15;
      ah[i] = *((const bf16x8*)&s_zh[r * LDT + lk]);
      al[i] = *((const bf16x8*)&s_zl[r * LDT + lk]);
    }
#pragma unroll
    for (int j = 0; j < 4; j++) {
      int c = wc * 64 + j * 16 + l15;
      bh[j] = *((const bf16x8*)&s_ch[c * LDT + lk]);
      bl[j] = *((const bf16x8*)&s_cl[c * LDT + lk]);
    }
#pragma unroll
    for (int i = 0; i < 4; i++)
#pragma unroll
      for (int j = 0; j < 4; j++)
        acc[i][j] = __builtin_amdgcn_mfma_f32_16x16x32_bf16(ah[i], bh[j], acc[i][j], 0, 0, 0);
#pragma unroll
    for (int i = 0; i < 4; i++)
#pragma unroll
      for (int j = 0; j < 4; j++)
        acc[i][j] = __builtin_amdgcn_mfma_f32_16x16x32_bf16(ah[i], bl[j], acc[i][j], 0, 0, 0);
#pragma unroll
    for (int i = 0; i < 4; i++)
#pragma unroll
      for (int j = 0; j < 4; j++)
        acc[i][j] = __builtin_amdgcn_mfma_f32_16x16x32_bf16(al[i], bh[j], acc[i][j], 0, 0, 0);
    __syncthreads();
  }

  // ---- epilogue: distances (reference rounding) + argmin, first-min tiebreak ----
#pragma unroll
  for (int i = 0; i < 4; i++) {
#pragma unroll
    for (int r = 0; r < 4; r++) {
      int lrow2 = wr * 64 + i * 16 + ((lane >> 4) << 2) + r;
      float l2v = s_l2[lrow2];
      float bv = 3.4e38f;
      int bk = 1 << 30;
#pragma unroll
      for (int j = 0; j < 4; j++) {
        int lcol = wc * 64 + j * 16 + l15;
        float dv = (l2v - 2.0f * acc[i][j][r]) + s_c2[lcol];
        if (dv < bv) { bv = dv; bk = lcol; }
      }
#pragma unroll
      for (int m = 1; m < 16; m <<= 1) {
        float ov = __shfl_xor(bv, m);
        int ok = __shfl_xor(bk, m);
        if (ov < bv || (ov == bv && ok < bk)) { bv = ov; bk = ok; }
      }
      if (l15 == 0) {
        s_wv[lrow2 * 2 + wc] = bv;
        s_wk[lrow2 * 2 + wc] = bk;
      }
    }
  }
  __syncthreads();
  if (tid < 128) {
    float v0 = s_wv[tid * 2], v1 = s_wv[tid * 2 + 1];
    int k0 = s_wk[tid * 2], k1 = s_wk[tid * 2 + 1];
    float bv = v0; int bk = k0;
    if (v1 < bv || (v1 == bv && k1 < bk)) { bv = v1; bk = k1; }
    pval[(size_t)codeblk * NR + row0 + tid] = bv;
    pidx[(size_t)codeblk * NR + row0 + tid] = code0 + bk;
  }
}

// ---------------- reduce partials + gather + losses + residual update ----------------
__global__ __launch_bounds__(256) void k_update(const float* __restrict__ zsrc,
                                                float* __restrict__ zdst,
                                                const float* __restrict__ cbS,
                                                const float* __restrict__ pval,
                                                const int* __restrict__ pidx,
                                                float* __restrict__ l2g,
                                                float* __restrict__ lpart) {
  __shared__ float lsh[4];
  int wid = threadIdx.x >> 6, lane = threadIdx.x & 63;
  int row = blockIdx.x * 4 + wid;
  float bv = pval[row];
  int bk = pidx[row];
#pragma unroll
  for (int c = 1; c < 8; ++c) {
    float v = pval[(size_t)c * NR + row];
    int k = pidx[(size_t)c * NR + row];
    if (v < bv) { bv = v; bk = k; }
  }
  float4 zv = ((const float4*)(zsrc + (size_t)row * DD))[lane];
  float4 cv = ((const float4*)(cbS + (size_t)bk * DD))[lane];
  float dx = cv.x - zv.x, dy = cv.y - zv.y, dz = cv.z - zv.z, dw = cv.w - zv.w;
  float ls = ((dx * dx + dy * dy) + (dz * dz + dw * dw));
  // codes_st = z + (codes - z); z_next = z - codes_st  (replicate reference rounding)
  float cstx = zv.x + dx, csty = zv.y + dy, cstz = zv.z + dz, cstw = zv.w + dw;
  float4 zn;
  zn.x = zv.x - cstx; zn.y = zv.y - csty; zn.z = zv.z - cstz; zn.w = zv.w - cstw;
  ((float4*)(zdst + (size_t)row * DD))[lane] = zn;
  double l2s = (double)zn.x * zn.x + (double)zn.y * zn.y + (double)zn.z * zn.z + (double)zn.w * zn.w;
  for (int off = 1; off < 64; off <<= 1) {
    l2s += __shfl_xor(l2s, off);
    ls += __shfl_xor(ls, off);
  }
  if (lane == 0) {
    l2g[row] = (float)l2s;
    lsh[wid] = ls;
  }
  __syncthreads();
  if (threadIdx.x == 0) lpart[blockIdx.x] = (lsh[0] + lsh[1]) + (lsh[2] + lsh[3]);
}

// ---------------- final_quantized = z0 - z3 ----------------
__global__ __launch_bounds__(256) void k_final(const float* __restrict__ z0,
                                               const float* __restrict__ z3,
                                               float* __restrict__ out) {
  size_t i = (size_t)blockIdx.x * 256 + threadIdx.x;
  float4 a = ((const float4*)z0)[i];
  float4 b = ((const float4*)z3)[i];
  float4 r;
  r.x = a.x - b.x; r.y = a.y - b.y; r.z = a.z - b.z; r.w = a.w - b.w;
  ((float4*)out)[i] = r;
}

// ---------------- losses ----------------
__global__ __launch_bounds__(256) void k_loss(const float* __restrict__ lpart,
                                              float* __restrict__ out) {
  int lane = threadIdx.x & 63, wid = threadIdx.x >> 6;
  __shared__ double sh[3][4];
  for (int s = 0; s < 3; ++s) {
    double acc = 0.0;
    for (int i = threadIdx.x; i < 16384; i += 256) acc += (double)lpart[s * 16384 + i];
    for (int off = 1; off < 64; off <<= 1) acc += __shfl_xor(acc, off);
    if (lane == 0) sh[s][wid] = acc;
  }
  __syncthreads();
  if (threadIdx.x == 0) {
    float loss = 0.0f;
    for (int s = 0; s < 3; ++s) {
      double t = (sh[s][0] + sh[s][1]) + (sh[s][2] + sh[s][3]);
      loss = loss + (float)(t / 16777216.0);
    }
    out[16777216] = loss;
    out[16777217] = loss;  // codebook_loss == commitment_loss in forward
  }
}

extern "C" void kernel_launch(void* const* d_in, const int* in_sizes, int n_in,
                              void* d_out, int out_size, void* d_ws, size_t ws_size,
                              hipStream_t stream) {
  const float* z0 = (const float*)d_in[0];
  const float* cbs = (const float*)d_in[1];
  float* out = (float*)d_out;
  char* ws = (char*)d_ws;
  float* zcur = (float*)ws;                                 // 64 MB
  float* pval = (float*)(ws + 67108864);                    // 2 MB
  int* pidx = (int*)(ws + 69206016);                        // 2 MB
  unsigned short* ch = (unsigned short*)(ws + 71303168);    // 1.5 MB
  unsigned short* cl = (unsigned short*)(ws + 72876032);    // 1.5 MB
  float* c2 = (float*)(ws + 74448896);                      // 12 KB
  float* l2 = (float*)(ws + 74461184);                      // 256 KB
  float* lpart = (float*)(ws + 74723328);                   // 192 KB

  k_prep<<<768, 256, 0, stream>>>(cbs, ch, cl, c2);
  k_l2<<<16384, 256, 0, stream>>>(z0, l2);
  for (int s = 0; s < 3; ++s) {
    const float* zin = (s == 0) ? z0 : zcur;
    k_gemm<<<4096, 256, 0, stream>>>(zin, ch + (size_t)s * KD, cl + (size_t)s * KD,
                                     c2 + s * KC, l2, pval, pidx);
    k_update<<<16384, 256, 0, stream>>>(zin, zcur, cbs + (size_t)s * KD, pval, pidx,
                                        l2, lpart + s * 16384);
  }
  k_final<<<16384, 256, 0, stream>>>(z0, zcur, out);
  k_loss<<<1, 256, 0, stream>>>(lpart, out);
}

// Round 2
// 556.465 us; speedup vs baseline: 1.4595x; 1.4595x over previous
//
#include <hip/hip_runtime.h>
#include <stdint.h>

#define NRR 65536
#define DDIM 256
#define KCODES 1024
#define KDSZ (KCODES * DDIM)
#define LDT 264  // padded LDS row stride in fp16 elems (528 B) -> 2-way-only bank aliasing

typedef __attribute__((ext_vector_type(8))) _Float16 f16x8;
typedef __attribute__((ext_vector_type(4))) float f32x4;

__device__ inline unsigned short f2h(float f) {
  _Float16 h = (_Float16)f;
  return __builtin_bit_cast(unsigned short, h);
}

// ---------------- codebook prep: fp16(1024*cb) + c2 (double -> f32) ----------------
__global__ __launch_bounds__(256) void k_prep(const float* __restrict__ cbs,
                                              _Float16* __restrict__ ch,
                                              float* __restrict__ c2) {
  int code = blockIdx.x * 4 + (threadIdx.x >> 6);  // 0..3071 over [3][1024]
  int lane = threadIdx.x & 63;
  float4 v = ((const float4*)(cbs + (size_t)code * DDIM))[lane];
  ushort4 u;
  u.x = f2h(v.x * 1024.0f);
  u.y = f2h(v.y * 1024.0f);
  u.z = f2h(v.z * 1024.0f);
  u.w = f2h(v.w * 1024.0f);
  ((ushort4*)((unsigned short*)ch + (size_t)code * DDIM))[lane] = u;
  double s = (double)v.x * v.x + (double)v.y * v.y + (double)v.z * v.z + (double)v.w * v.w;
  for (int off = 1; off < 64; off <<= 1) s += __shfl_xor(s, off);
  if (lane == 0) c2[code] = (float)s;
}

// ---------------- fused 3-stage RVQ: stage->gemm->argmin->update, all in one ----------------
// grid 512 blocks x 256 threads; each block owns 128 rows for all 3 stages.
__global__ __launch_bounds__(256, 2) void k_rvq(const float* __restrict__ z0,
                                                const float* __restrict__ cbs,
                                                const _Float16* __restrict__ ch,
                                                const float* __restrict__ c2,
                                                float* zcur,
                                                float* __restrict__ outq,
                                                float* __restrict__ lpart) {
  __shared__ _Float16 s_z[128 * LDT];  // 66 KiB
  __shared__ float s_l2[128];
  __shared__ float s_wv[256];
  __shared__ int s_wk[256];
  __shared__ int s_bk[128];
  __shared__ float s_ls[4];

  const int tid = threadIdx.x;
  const int wid = tid >> 6;
  const int lane = tid & 63;
  const int l15 = lane & 15;
  const int wr = wid >> 1, wc = wid & 1;
  const int lk = (lane >> 4) * 8;  // k offset within 32-chunk
  const size_t gbase = (size_t)blockIdx.x * 128 * DDIM;

  for (int s = 0; s < 3; ++s) {
    const float* zsrc = (s == 0) ? z0 : zcur;

    // ---- staging: z fp32 -> fp16 LDS, fused per-row l2 (double -> f32) ----
    for (int it = 0; it < 32; ++it) {
      int elem = it * 1024 + tid * 4;
      int row = it * 4 + wid;       // one row per wave per iteration
      int col = (tid & 63) * 4;
      float4 v = *(const float4*)(zsrc + gbase + elem);
      ushort4 u;
      u.x = f2h(v.x); u.y = f2h(v.y); u.z = f2h(v.z); u.w = f2h(v.w);
      *(ushort4*)(&s_z[row * LDT + col]) = u;
      double d2 = (double)v.x * v.x + (double)v.y * v.y + (double)v.z * v.z + (double)v.w * v.w;
      for (int m = 1; m < 64; m <<= 1) d2 += __shfl_xor(d2, m);
      if (lane == 0) s_l2[row] = (float)d2;
    }
    __syncthreads();

    // ---- gemm (single-pass fp16 MFMA, codebook pre-scaled x1024) + argmin ----
    float bv[4][4];
    int bk[4][4];
#pragma unroll
    for (int i = 0; i < 4; i++)
#pragma unroll
      for (int r = 0; r < 4; r++) { bv[i][r] = 3.4e38f; bk[i][r] = 0x3FFFFFFF; }

    const _Float16* chS = ch + (size_t)s * KDSZ;
    const float* c2S = c2 + s * KCODES;

    for (int cb = 0; cb < 8; ++cb) {
      f32x4 acc[4][4];
#pragma unroll
      for (int i = 0; i < 4; i++)
#pragma unroll
        for (int j = 0; j < 4; j++) acc[i][j] = f32x4{0.f, 0.f, 0.f, 0.f};

      const int codeBase = cb * 128 + wc * 64;
      const _Float16* bp0 = chS + (size_t)(codeBase + l15) * DDIM;

#pragma unroll
      for (int kc = 0; kc < 8; ++kc) {
        f16x8 a[4], b[4];
#pragma unroll
        for (int i = 0; i < 4; i++) {
          int r = wr * 64 + i * 16 + l15;
          a[i] = *(const f16x8*)(&s_z[r * LDT + kc * 32 + lk]);
        }
#pragma unroll
        for (int j = 0; j < 4; j++)
          b[j] = *(const f16x8*)(bp0 + (size_t)j * 16 * DDIM + kc * 32 + lk);
#pragma unroll
        for (int i = 0; i < 4; i++)
#pragma unroll
          for (int j = 0; j < 4; j++)
            acc[i][j] = __builtin_amdgcn_mfma_f32_16x16x32_f16(a[i], b[j], acc[i][j], 0, 0, 0);
      }

      // running argmin (codes ascend with cb,j for fixed lane -> strict < = first-min)
#pragma unroll
      for (int j = 0; j < 4; j++) {
        int kcode = codeBase + j * 16 + l15;
        float c2v = c2S[kcode];
#pragma unroll
        for (int i = 0; i < 4; i++) {
          int lrow = wr * 64 + i * 16 + ((lane >> 4) << 2);
#pragma unroll
          for (int r = 0; r < 4; r++) {
            // 2S = acc * 2^-9 (exact): d = (l2 - 2S) + c2, reference association
            float dv = (s_l2[lrow + r] - acc[i][j][r] * 0.001953125f) + c2v;
            if (dv < bv[i][r]) { bv[i][r] = dv; bk[i][r] = kcode; }
          }
        }
      }
    }

    // cross-lane argmin within 16-lane col groups, then across wc halves
#pragma unroll
    for (int i = 0; i < 4; i++)
#pragma unroll
      for (int r = 0; r < 4; r++) {
        float v = bv[i][r];
        int k = bk[i][r];
#pragma unroll
        for (int m = 1; m < 16; m <<= 1) {
          float ov = __shfl_xor(v, m);
          int ok = __shfl_xor(k, m);
          if (ov < v || (ov == v && ok < k)) { v = ov; k = ok; }
        }
        int lrow = wr * 64 + i * 16 + ((lane >> 4) << 2) + r;
        if (l15 == 0) { s_wv[lrow * 2 + wc] = v; s_wk[lrow * 2 + wc] = k; }
      }
    __syncthreads();
    if (tid < 128) {
      float v0 = s_wv[tid * 2], v1 = s_wv[tid * 2 + 1];
      int k0 = s_wk[tid * 2], k1 = s_wk[tid * 2 + 1];
      s_bk[tid] = (v1 < v0 || (v1 == v0 && k1 < k0)) ? k1 : k0;
    }
    __syncthreads();

    // ---- epilogue: gather + losses + residual (exact fp32 reference rounding) ----
    float lacc = 0.f;
    const float* cbsS = cbs + (size_t)s * KDSZ;
    for (int it = 0; it < 32; ++it) {
      int elem = it * 1024 + tid * 4;
      int row = it * 4 + wid;
      float4 zv = *(const float4*)(zsrc + gbase + elem);
      int code = s_bk[row];
      float4 cv = *(const float4*)(cbsS + (size_t)code * DDIM + (elem & 255));
      float tx = cv.x - zv.x, ty = cv.y - zv.y, tz = cv.z - zv.z, tw = cv.w - zv.w;
      lacc += (tx * tx + ty * ty) + (tz * tz + tw * tw);
      float cstx = zv.x + tx, csty = zv.y + ty, cstz = zv.z + tz, cstw = zv.w + tw;
      float znx = zv.x - cstx, zny = zv.y - csty, znz = zv.z - cstz, znw = zv.w - cstw;
      if (s < 2) {
        float4 o; o.x = znx; o.y = zny; o.z = znz; o.w = znw;
        *(float4*)(zcur + gbase + elem) = o;  // in-place safe: same thread, same elems
      } else {
        float4 a = *(const float4*)(z0 + gbase + elem);
        float4 o; o.x = a.x - znx; o.y = a.y - zny; o.z = a.z - znz; o.w = a.w - znw;
        *(float4*)(outq + gbase + elem) = o;  // out = z0 - z3
      }
    }
    for (int m = 1; m < 64; m <<= 1) lacc += __shfl_xor(lacc, m);
    if (lane == 0) s_ls[wid] = lacc;
    __syncthreads();
    if (tid == 0) lpart[s * 512 + blockIdx.x] = (s_ls[0] + s_ls[1]) + (s_ls[2] + s_ls[3]);
    __syncthreads();  // protect s_z/s_ls before next stage overwrites
  }
}

// ---------------- losses: double-sum 512 block partials per stage ----------------
__global__ __launch_bounds__(256) void k_loss(const float* __restrict__ lpart,
                                              float* __restrict__ out) {
  int lane = threadIdx.x & 63, wid = threadIdx.x >> 6;
  __shared__ double sh[3][4];
  for (int s = 0; s < 3; ++s) {
    double a = (double)lpart[s * 512 + threadIdx.x] + (double)lpart[s * 512 + 256 + threadIdx.x];
    for (int off = 1; off < 64; off <<= 1) a += __shfl_xor(a, off);
    if (lane == 0) sh[s][wid] = a;
  }
  __syncthreads();
  if (threadIdx.x == 0) {
    float loss = 0.0f;
    for (int s = 0; s < 3; ++s) {
      double t = (sh[s][0] + sh[s][1]) + (sh[s][2] + sh[s][3]);
      loss = loss + (float)(t / 16777216.0);
    }
    out[16777216] = loss;
    out[16777217] = loss;  // codebook_loss == commitment_loss in forward
  }
}

extern "C" void kernel_launch(void* const* d_in, const int* in_sizes, int n_in,
                              void* d_out, int out_size, void* d_ws, size_t ws_size,
                              hipStream_t stream) {
  const float* z0 = (const float*)d_in[0];
  const float* cbs = (const float*)d_in[1];
  float* out = (float*)d_out;
  char* ws = (char*)d_ws;
  float* zcur = (float*)ws;                          // 64 MB
  _Float16* ch = (_Float16*)(ws + 67108864);         // 1.5 MB
  float* c2 = (float*)(ws + 68681728);               // 12 KB
  float* lpart = (float*)(ws + 68694016);            // 6 KB

  k_prep<<<768, 256, 0, stream>>>(cbs, ch, c2);
  k_rvq<<<512, 256, 0, stream>>>(z0, cbs, ch, c2, zcur, out, lpart);
  k_loss<<<1, 256, 0, stream>>>(lpart, out);
}

// Round 3
// 433.124 us; speedup vs baseline: 1.8752x; 1.2848x over previous
//
#include <hip/hip_runtime.h>
#include <stdint.h>

#define DDIM 256
#define KCODES 1024
#define KDSZ (KCODES * DDIM)
#define ROWS 64
#define LDT 264  // LDS row stride (528 B): 2-way-only bank aliasing on frag reads

typedef __attribute__((ext_vector_type(8))) _Float16 f16x8;
typedef __attribute__((ext_vector_type(4))) float f32x4;

__device__ inline unsigned short f2h(float f) {
  _Float16 h = (_Float16)f;
  return __builtin_bit_cast(unsigned short, h);
}

// ---- codebook prep: ch = fp16(-1024*cb), c2h = 512*||cb||^2 ----
// key = 512*c2 - 1024*S = 512*(c2 - 2S): same argmin as reference distances.
__global__ __launch_bounds__(256) void k_prep(const float* __restrict__ cbs,
                                              _Float16* __restrict__ ch,
                                              float* __restrict__ c2h) {
  int code = blockIdx.x * 4 + (threadIdx.x >> 6);  // 0..3071 over [3][1024]
  int lane = threadIdx.x & 63;
  float4 v = ((const float4*)(cbs + (size_t)code * DDIM))[lane];
  ushort4 u;
  u.x = f2h(v.x * -1024.0f);
  u.y = f2h(v.y * -1024.0f);
  u.z = f2h(v.z * -1024.0f);
  u.w = f2h(v.w * -1024.0f);
  ((ushort4*)((unsigned short*)ch + (size_t)code * DDIM))[lane] = u;
  double s = (double)v.x * v.x + (double)v.y * v.y + (double)v.z * v.z + (double)v.w * v.w;
  for (int off = 1; off < 64; off <<= 1) s += __shfl_xor(s, off);
  if (lane == 0) c2h[code] = (float)(s * 512.0);
}

// ---- fused 3-stage RVQ, z register-resident, swapped-operand MFMA argmin ----
// grid 1024 blocks x 256 threads; block owns 64 rows; waves split the 1024 codes 4-way.
__global__ __launch_bounds__(256, 2) void k_rvq(const float* __restrict__ z0,
                                                const float* __restrict__ cbs,
                                                const _Float16* __restrict__ ch,
                                                const float* __restrict__ c2h,
                                                float* __restrict__ outq,
                                                float* __restrict__ lpart) {
  __shared__ _Float16 s_z[ROWS * LDT];  // 33 KiB fp16 z-tile
  __shared__ float s_wv[4 * ROWS];
  __shared__ int s_wk[4 * ROWS];
  __shared__ int s_bk[ROWS];
  __shared__ float s_ls[4];

  const int tid = threadIdx.x;
  const int wid = tid >> 6;
  const int lane = tid & 63;
  const int l15 = lane & 15;
  const int lg = lane >> 4;  // 16-lane group 0..3
  const size_t gbase = (size_t)blockIdx.x * ROWS * DDIM;

  // z0 -> registers, fully coalesced (1 KB/wave/instr). f[i] = row i*4+wid, cols lane*4..+4
  float4 f[16];
#pragma unroll
  for (int i = 0; i < 16; ++i)
    f[i] = *(const float4*)(z0 + gbase + i * 1024 + tid * 4);

  for (int s = 0; s < 3; ++s) {
    // ---- staging: registers -> fp16 LDS (no global traffic, no reductions) ----
#pragma unroll
    for (int i = 0; i < 16; ++i) {
      float4 zv = f[i];
      ushort4 u;
      u.x = f2h(zv.x); u.y = f2h(zv.y); u.z = f2h(zv.z); u.w = f2h(zv.w);
      *(ushort4*)(&s_z[(i * 4 + wid) * LDT + lane * 4]) = u;
    }
    __syncthreads();

    // ---- gemm S^T = (-1024*cb) . z^T with acc init = 512*c2; running argmin ----
    const _Float16* chS = ch + (size_t)s * KDSZ;
    const float* c2S = c2h + s * KCODES;
    float bv[4];
    int bk[4];
#pragma unroll
    for (int i = 0; i < 4; ++i) { bv[i] = 3.4e38f; bk[i] = 0x3FFFFFFF; }

    const int code00 = wid * 256;  // each wave owns 256 consecutive codes
    for (int cb2 = 0; cb2 < 4; ++cb2) {
      const int codeB = code00 + cb2 * 64;
      // acc[i][j]: zrow-frag i (rows i*16+l15), code-frag j (codes codeB+j*16+..)
      f32x4 acc[4][4];
#pragma unroll
      for (int j = 0; j < 4; ++j) {
        float4 ci = *(const float4*)(c2S + codeB + j * 16 + lg * 4);
        f32x4 cv = {ci.x, ci.y, ci.z, ci.w};
#pragma unroll
        for (int i = 0; i < 4; ++i) acc[i][j] = cv;
      }
#pragma unroll
      for (int kc = 0; kc < 8; ++kc) {
        f16x8 a[4], b[4];
#pragma unroll
        for (int j = 0; j < 4; ++j)
          a[j] = *(const f16x8*)(chS + (size_t)(codeB + j * 16 + l15) * DDIM + kc * 32 + lg * 8);
#pragma unroll
        for (int i = 0; i < 4; ++i)
          b[i] = *(const f16x8*)(&s_z[(i * 16 + l15) * LDT + kc * 32 + lg * 8]);
#pragma unroll
        for (int i = 0; i < 4; ++i)
#pragma unroll
          for (int j = 0; j < 4; ++j)
            acc[i][j] = __builtin_amdgcn_mfma_f32_16x16x32_f16(a[j], b[i], acc[i][j], 0, 0, 0);
      }
      // lane-local running argmin; traversal (cb2, j, r) ascending -> strict < = first-min
#pragma unroll
      for (int j = 0; j < 4; ++j) {
#pragma unroll
        for (int r = 0; r < 4; ++r) {
          int kcode = codeB + j * 16 + lg * 4 + r;
#pragma unroll
          for (int i = 0; i < 4; ++i) {
            float v = acc[i][j][r];
            if (v < bv[i]) { bv[i] = v; bk[i] = kcode; }
          }
        }
      }
    }

    // reduce across the 4 lane-groups (codes split by lg), tie-break lower index
#pragma unroll
    for (int m = 16; m <= 32; m <<= 1) {
#pragma unroll
      for (int i = 0; i < 4; ++i) {
        float ov = __shfl_xor(bv[i], m);
        int ok = __shfl_xor(bk[i], m);
        if (ov < bv[i] || (ov == bv[i] && ok < bk[i])) { bv[i] = ov; bk[i] = ok; }
      }
    }
    if (lane < 16) {
#pragma unroll
      for (int i = 0; i < 4; ++i) {
        s_wv[wid * ROWS + i * 16 + lane] = bv[i];
        s_wk[wid * ROWS + i * 16 + lane] = bk[i];
      }
    }
    __syncthreads();
    // final: min over the 4 waves' code-slices per zrow
    if (tid < ROWS) {
      float v = s_wv[tid];
      int k = s_wk[tid];
#pragma unroll
      for (int w = 1; w < 4; ++w) {
        float vv = s_wv[w * ROWS + tid];
        int kk = s_wk[w * ROWS + tid];
        if (vv < v || (vv == v && kk < k)) { v = vv; k = kk; }
      }
      s_bk[tid] = k;
    }
    __syncthreads();

    // ---- epilogue: gather + losses + residual update in registers ----
    float lacc = 0.f;
    const float* cbsS = cbs + (size_t)s * KDSZ;
#pragma unroll
    for (int i = 0; i < 16; ++i) {
      int row = i * 4 + wid;
      int code = s_bk[row];
      float4 cv = *(const float4*)(cbsS + (size_t)code * DDIM + lane * 4);
      float4 zv = f[i];
      float tx = cv.x - zv.x, ty = cv.y - zv.y, tz = cv.z - zv.z, tw = cv.w - zv.w;
      lacc += (tx * tx + ty * ty) + (tz * tz + tw * tw);
      float cstx = zv.x + tx, csty = zv.y + ty, cstz = zv.z + tz, cstw = zv.w + tw;
      float znx = zv.x - cstx, zny = zv.y - csty, znz = zv.z - cstz, znw = zv.w - cstw;
      if (s < 2) {
        f[i].x = znx; f[i].y = zny; f[i].z = znz; f[i].w = znw;
      } else {
        float4 a = *(const float4*)(z0 + gbase + i * 1024 + tid * 4);
        float4 o;
        o.x = a.x - znx; o.y = a.y - zny; o.z = a.z - znz; o.w = a.w - znw;
        *(float4*)(outq + gbase + i * 1024 + tid * 4) = o;  // out = z0 - z3
      }
    }
    for (int m = 1; m < 64; m <<= 1) lacc += __shfl_xor(lacc, m);
    if (lane == 0) s_ls[wid] = lacc;
    __syncthreads();
    if (tid == 0) lpart[s * 1024 + blockIdx.x] = (s_ls[0] + s_ls[1]) + (s_ls[2] + s_ls[3]);
    __syncthreads();  // s_ls/s_bk consumed before next stage reuses LDS
  }
}

// ---- losses: double-sum 1024 block partials per stage ----
__global__ __launch_bounds__(256) void k_loss(const float* __restrict__ lpart,
                                              float* __restrict__ out) {
  int lane = threadIdx.x & 63, wid = threadIdx.x >> 6;
  __shared__ double sh[3][4];
  for (int s = 0; s < 3; ++s) {
    double a = 0.0;
    for (int idx = threadIdx.x; idx < 1024; idx += 256) a += (double)lpart[s * 1024 + idx];
    for (int off = 1; off < 64; off <<= 1) a += __shfl_xor(a, off);
    if (lane == 0) sh[s][wid] = a;
  }
  __syncthreads();
  if (threadIdx.x == 0) {
    float loss = 0.0f;
    for (int s = 0; s < 3; ++s) {
      double t = (sh[s][0] + sh[s][1]) + (sh[s][2] + sh[s][3]);
      loss = loss + (float)(t / 16777216.0);
    }
    out[16777216] = loss;
    out[16777217] = loss;  // codebook_loss == commitment_loss in forward
  }
}

extern "C" void kernel_launch(void* const* d_in, const int* in_sizes, int n_in,
                              void* d_out, int out_size, void* d_ws, size_t ws_size,
                              hipStream_t stream) {
  const float* z0 = (const float*)d_in[0];
  const float* cbs = (const float*)d_in[1];
  float* out = (float*)d_out;
  char* ws = (char*)d_ws;
  _Float16* ch = (_Float16*)ws;              // 1.5 MB
  float* c2h = (float*)(ws + 1572864);       // 12 KB
  float* lpart = (float*)(ws + 1585152);     // 12 KB

  k_prep<<<768, 256, 0, stream>>>(cbs, ch, c2h);
  k_rvq<<<1024, 256, 0, stream>>>(z0, cbs, ch, c2h, out, lpart);
  k_loss<<<1, 256, 0, stream>>>(lpart, out);
}